// Round 7
// baseline (177.210 us; speedup 1.0000x reference)
//
#include <hip/hip_runtime.h>
#include <math.h>

#define C_DIMK 2048

typedef float f32x4 __attribute__((ext_vector_type(4)));

// Fully-resident streamer: 512 blocks (exactly 2/CU, one generation, no block
// turnover). Block b owns output rows r0..r0+3 (r0 = 4b). Wave w streams rows
// r0..r0+3 of gate-w's weight matrix (64 KB contiguous) through a 2-deep
// ping-pong register pipeline: issue row k+1's 16 NT loads while computing
// row k's dot. sched_barrier(0) fences each batch so the compiler cannot
// collapse the in-flight depth. cat(x,h) is staged to LDS BEFORE any weight
// load issues (the barrier's vmcnt(0) drain then only covers the 4 tiny
// x/h loads, leaving the weight pipeline unbroken).

#define ISSUE_ROW(buf, rowptr)                                         \
  _Pragma("unroll")                                                    \
  for (int j = 0; j < 16; ++j)                                         \
    buf[j] = __builtin_nontemporal_load(&(rowptr)[j * 64 + lane]);

#define DOT_ROW(buf, acc)                                              \
  {                                                                    \
    float d0 = 0.f, d1 = 0.f, d2 = 0.f, d3 = 0.f;                      \
    _Pragma("unroll")                                                  \
    for (int j = 0; j < 16; ++j) {                                     \
      const f32x4 xvj = xs[j * 64 + lane];                             \
      const f32x4 wv = buf[j];                                         \
      float d = wv.x * xvj.x;                                          \
      d = fmaf(wv.y, xvj.y, d);                                        \
      d = fmaf(wv.z, xvj.z, d);                                        \
      d = fmaf(wv.w, xvj.w, d);                                        \
      if ((j & 3) == 0) d0 += d;                                       \
      else if ((j & 3) == 1) d1 += d;                                  \
      else if ((j & 3) == 2) d2 += d;                                  \
      else d3 += d;                                                    \
    }                                                                  \
    acc = (d0 + d1) + (d2 + d3);                                       \
  }

__global__ __launch_bounds__(256, 2) void lstm_fused_kernel(
    const float* __restrict__ h, const float* __restrict__ c,
    const float* __restrict__ x,
    const float* __restrict__ wf, const float* __restrict__ bf,
    const float* __restrict__ wi, const float* __restrict__ bi,
    const float* __restrict__ wo, const float* __restrict__ bo,
    const float* __restrict__ wc, const float* __restrict__ bc,
    float* __restrict__ out)
{
    __shared__ f32x4 xs[1024];          // 16 KB: cat(x, h)
    __shared__ float partial[4][4];     // [wave][row]

    const int t    = threadIdx.x;
    const int wave = t >> 6;            // 0..3 -> gate f,i,c,o
    const int lane = t & 63;
    const int r0   = blockIdx.x * 4;

    // Stage cat(x,h) to LDS first; barrier drains only these 4 loads.
    const f32x4* X4 = reinterpret_cast<const f32x4*>(x);
    const f32x4* H4 = reinterpret_cast<const f32x4*>(h);
    #pragma unroll
    for (int k = 0; k < 4; ++k) {
        const int idx = k * 256 + t;    // 0..1023; k<2 -> x, k>=2 -> h (uniform)
        xs[idx] = (idx < 512) ? X4[idx] : H4[idx - 512];
    }
    __syncthreads();

    // Gate order matches reference g-layout: [f, i, c, o]
    const float* W = (wave == 0) ? wf : (wave == 1) ? wi : (wave == 2) ? wc : wo;
    const f32x4* Wm = reinterpret_cast<const f32x4*>(W);
    const f32x4* row0 = Wm + (size_t)(r0 + 0) * 1024;
    const f32x4* row1 = Wm + (size_t)(r0 + 1) * 1024;
    const f32x4* row2 = Wm + (size_t)(r0 + 2) * 1024;
    const f32x4* row3 = Wm + (size_t)(r0 + 3) * 1024;

    f32x4 bufA[16], bufB[16];
    float s0, s1, s2, s3;

    ISSUE_ROW(bufA, row0);
    __builtin_amdgcn_sched_barrier(0);
    ISSUE_ROW(bufB, row1);
    __builtin_amdgcn_sched_barrier(0);
    DOT_ROW(bufA, s0);                  // waits vmcnt<=16: row1 stays in flight
    __builtin_amdgcn_sched_barrier(0);
    ISSUE_ROW(bufA, row2);
    __builtin_amdgcn_sched_barrier(0);
    DOT_ROW(bufB, s1);
    __builtin_amdgcn_sched_barrier(0);
    ISSUE_ROW(bufB, row3);
    __builtin_amdgcn_sched_barrier(0);
    DOT_ROW(bufA, s2);
    __builtin_amdgcn_sched_barrier(0);
    DOT_ROW(bufB, s3);

    // Wave64 reductions for the 4 row partials.
    #pragma unroll
    for (int off = 32; off > 0; off >>= 1) {
        s0 += __shfl_down(s0, off, 64);
        s1 += __shfl_down(s1, off, 64);
        s2 += __shfl_down(s2, off, 64);
        s3 += __shfl_down(s3, off, 64);
    }

    if (lane == 0) {
        partial[wave][0] = s0;
        partial[wave][1] = s1;
        partial[wave][2] = s2;
        partial[wave][3] = s3;
    }
    __syncthreads();

    if (t < 4) {
        const int r = r0 + t;
        const float gf = partial[0][t] + bf[r];
        const float gi = partial[1][t] + bi[r];
        const float gc = partial[2][t] + bc[r];
        const float go = partial[3][t] + bo[r];
        const float ff = 1.0f / (1.0f + __expf(-gf));
        const float ig = 1.0f / (1.0f + __expf(-gi));
        const float cc = tanhf(gc);
        const float oo = 1.0f / (1.0f + __expf(-go));
        const float cn = fmaf(ff, c[r], ig * cc);
        const float hn = tanhf(cn) * oo;
        out[r]          = cn;   // c_new
        out[C_DIMK + r] = hn;   // h_new
    }
}

extern "C" void kernel_launch(void* const* d_in, const int* in_sizes, int n_in,
                              void* d_out, int out_size, void* d_ws, size_t ws_size,
                              hipStream_t stream) {
    // setup_inputs() order: h, c, x, wf, bf, wi, bi, wo, bo, wc, bc (all fp32)
    const float* h  = (const float*)d_in[0];
    const float* c  = (const float*)d_in[1];
    const float* x  = (const float*)d_in[2];
    const float* wf = (const float*)d_in[3];
    const float* bf = (const float*)d_in[4];
    const float* wi = (const float*)d_in[5];
    const float* bi = (const float*)d_in[6];
    const float* wo = (const float*)d_in[7];
    const float* bo = (const float*)d_in[8];
    const float* wc = (const float*)d_in[9];
    const float* bc = (const float*)d_in[10];
    float* out = (float*)d_out;

    lstm_fused_kernel<<<512, 256, 0, stream>>>(
        h, c, x, wf, bf, wi, bi, wo, bo, wc, bc, out);
}